// Round 1
// baseline (193.480 us; speedup 1.0000x reference)
//
#include <hip/hip_runtime.h>

// GraphAugmentation fused kernel, MI355X.
//
// Key algebraic facts (see session theory):
//  * softmax over 8 identical affinities == uniform 1/8  -> Q/K/attn are dead.
//  * agg = conv1x1(mean_of_8_rolls(x), mw, mb)  (roll commutes with 1x1 conv).
//  * out = agg * sigmoid(g2 @ relu(g1 @ [x; agg]))
//
// B=4, C=16, H=W=512, GH=32. All f32. One block per (b,h) row, 256 threads,
// each thread owns pixels w=tid and w=tid+256 (P=2 interleave to amortize
// weight loads; both halves coalesced).

#define HW 262144   // 512*512
#define WD 512

__global__ __launch_bounds__(256) void ga_fused(
    const float* __restrict__ x,
    const float* __restrict__ mw,  const float* __restrict__ mb,
    const float* __restrict__ g1w, const float* __restrict__ g1b,
    const float* __restrict__ g2w, const float* __restrict__ g2b,
    float* __restrict__ out)
{
  // Fixed offsets (dy,dx) from the reference OFFSETS list.
  constexpr int DY[8] = {-4, -4, -4, -3, -2, 2, 3, 4};
  constexpr int DX[8] = {-4, -1,  2,  4, -3, 3, -2, 4};

  const int bh = blockIdx.x;      // 0..2047
  const int b  = bh >> 9;         // 0..3
  const int h  = bh & 511;
  const int t  = threadIdx.x;
  const int w0 = t;
  const int w1 = t + 256;

  // Neighbor row offsets (wave-uniform) and per-lane wrapped columns.
  int roff[8], c0[8], c1[8];
#pragma unroll
  for (int i = 0; i < 8; ++i) {
    roff[i] = ((h - DY[i]) & 511) * WD;
    c0[i]   = (w0 - DX[i]) & 511;
    c1[i]   = (w1 - DX[i]) & 511;
  }

  const float* xb = x + b * 16 * HW;
  const int rowbase = h * WD;

  // ---- load center x and compute xavg (mean over the 8 rolled copies) ----
  float xc0[16], xc1[16], xa0[16], xa1[16];
#pragma unroll
  for (int c = 0; c < 16; ++c) {
    const float* xp = xb + c * HW;
    xc0[c] = xp[rowbase + w0];
    xc1[c] = xp[rowbase + w1];
    float s0 = 0.f, s1 = 0.f;
#pragma unroll
    for (int i = 0; i < 8; ++i) {
      s0 += xp[roff[i] + c0[i]];
      s1 += xp[roff[i] + c1[i]];
    }
    xa0[c] = s0 * 0.125f;
    xa1[c] = s1 * 0.125f;
  }

  // ---- agg = mw @ xavg + mb  (16x16) ----
  float ag0[16], ag1[16];
#pragma unroll
  for (int c = 0; c < 16; ++c) {
    float a0 = mb[c], a1 = mb[c];
#pragma unroll
    for (int k = 0; k < 16; ++k) {
      const float wv = mw[c * 16 + k];     // wave-uniform -> s_load expected
      a0 = fmaf(wv, xa0[k], a0);
      a1 = fmaf(wv, xa1[k], a1);
    }
    ag0[c] = a0;
    ag1[c] = a1;
  }

  // ---- hidden = relu(g1w @ [x; agg] + g1b)  (32x32) ----
  float hd0[32], hd1[32];
#pragma unroll
  for (int j = 0; j < 32; ++j) {
    float s0 = g1b[j], s1 = g1b[j];
#pragma unroll
    for (int k = 0; k < 16; ++k) {
      const float wx = g1w[j * 32 + k];
      const float wa = g1w[j * 32 + 16 + k];
      s0 = fmaf(wx, xc0[k], s0);
      s0 = fmaf(wa, ag0[k], s0);
      s1 = fmaf(wx, xc1[k], s1);
      s1 = fmaf(wa, ag1[k], s1);
    }
    hd0[j] = fmaxf(s0, 0.f);
    hd1[j] = fmaxf(s1, 0.f);
  }

  // ---- gate = sigmoid(g2w @ hidden + g2b); out = agg * gate  (16x32) ----
  float* ob = out + b * 16 * HW + rowbase;
#pragma unroll
  for (int c = 0; c < 16; ++c) {
    float s0 = g2b[c], s1 = g2b[c];
#pragma unroll
    for (int j = 0; j < 32; ++j) {
      const float wv = g2w[c * 32 + j];
      s0 = fmaf(wv, hd0[j], s0);
      s1 = fmaf(wv, hd1[j], s1);
    }
    const float gt0 = 1.0f / (1.0f + __expf(-s0));
    const float gt1 = 1.0f / (1.0f + __expf(-s1));
    ob[c * HW + w0] = ag0[c] * gt0;
    ob[c * HW + w1] = ag1[c] * gt1;
  }
}

extern "C" void kernel_launch(void* const* d_in, const int* in_sizes, int n_in,
                              void* d_out, int out_size, void* d_ws, size_t ws_size,
                              hipStream_t stream) {
  // setup_inputs() order:
  // 0:x 1:qw 2:qb 3:kw 4:kb 5:mw 6:mb 7:scaling 8:g1w 9:g1b 10:g2w 11:g2b
  const float* x   = (const float*)d_in[0];
  const float* mw  = (const float*)d_in[5];
  const float* mb  = (const float*)d_in[6];
  const float* g1w = (const float*)d_in[8];
  const float* g1b = (const float*)d_in[9];
  const float* g2w = (const float*)d_in[10];
  const float* g2b = (const float*)d_in[11];
  float* out = (float*)d_out;

  // grid: one block per (b, h) row; 4*512 = 2048 blocks.
  ga_fused<<<2048, 256, 0, stream>>>(x, mw, mb, g1w, g1b, g2w, g2b, out);
}